// Round 1
// baseline (351.716 us; speedup 1.0000x reference)
//
#include <hip/hip_runtime.h>
#include <hip/hip_bf16.h>
#include <stdint.h>

// ---------------------------------------------------------------------------
// SSD (Mamba-2 chunked scan) for B=2, L=4096, DM=1024, NH=32, HD=32, DS=64,
// CS=256.  All heavy matmuls in bf16 MFMA (16x16x32), fp32 accumulation.
// ---------------------------------------------------------------------------

typedef __bf16 bf16x8 __attribute__((ext_vector_type(8)));
typedef __bf16 bf16x4 __attribute__((ext_vector_type(4)));
typedef float  f32x4  __attribute__((ext_vector_type(4)));

#define MFMA16(a, b, c) __builtin_amdgcn_mfma_f32_16x16x32_bf16((a), (b), (c), 0, 0, 0)

// ---------------------------------------------------------------------------
// fp32 -> bf16 convert (4 elements / thread)
// ---------------------------------------------------------------------------
__global__ void cvt_f32_bf16(const float* __restrict__ in, __bf16* __restrict__ out, int n) {
    int i = (blockIdx.x * 256 + threadIdx.x) * 4;
    if (i + 3 < n) {
        float4 v = *(const float4*)(in + i);
        bf16x4 o;
        o[0] = (__bf16)v.x; o[1] = (__bf16)v.y; o[2] = (__bf16)v.z; o[3] = (__bf16)v.w;
        *(bf16x4*)(out + i) = o;
    } else {
        for (int k = i; k < n; ++k) out[k] = (__bf16)in[k];
    }
}

// ---------------------------------------------------------------------------
// GEMM: C[M x Nvalid] (fp32) = A[M x K] (bf16) @ Bt[Nrows x K]^T (bf16)
// 128x128 block tile, BK=32, 4 waves (2x2), each wave 4x4 MFMA tiles.
// ---------------------------------------------------------------------------
__global__ __launch_bounds__(256) void gemm_bt(
    const __bf16* __restrict__ A, const __bf16* __restrict__ Bt,
    float* __restrict__ C, int K, int Nrows, int Nvalid)
{
    __shared__ __attribute__((aligned(16))) __bf16 As[128 * 32];
    __shared__ __attribute__((aligned(16))) __bf16 Bs[128 * 32];
    const int tid = threadIdx.x;
    const int m0 = blockIdx.y * 128;
    const int n0 = blockIdx.x * 128;
    const int r  = tid >> 2;
    const int c8 = (tid & 3) * 8;
    const int wave = tid >> 6, lane = tid & 63;
    const int wm = wave >> 1, wn = wave & 1;
    const int fr = lane & 15, fk = (lane >> 4) * 8;

    const int br0 = min(n0 + r, Nrows - 1);
    const int br1 = min(n0 + 64 + r, Nrows - 1);

    f32x4 acc[4][4] = {};

    for (int kt = 0; kt < K; kt += 32) {
        ((int4*)As)[tid]       = *(const int4*)(A + (size_t)(m0 + r) * K + kt + c8);
        ((int4*)As)[256 + tid] = *(const int4*)(A + (size_t)(m0 + 64 + r) * K + kt + c8);
        ((int4*)Bs)[tid]       = *(const int4*)(Bt + (size_t)br0 * K + kt + c8);
        ((int4*)Bs)[256 + tid] = *(const int4*)(Bt + (size_t)br1 * K + kt + c8);
        __syncthreads();
        bf16x8 af[4], bfv[4];
#pragma unroll
        for (int a = 0; a < 4; ++a)
            af[a] = *(const bf16x8*)&As[(wm * 64 + a * 16 + fr) * 32 + fk];
#pragma unroll
        for (int b = 0; b < 4; ++b)
            bfv[b] = *(const bf16x8*)&Bs[(wn * 64 + b * 16 + fr) * 32 + fk];
#pragma unroll
        for (int a = 0; a < 4; ++a)
#pragma unroll
            for (int b = 0; b < 4; ++b)
                acc[a][b] = MFMA16(af[a], bfv[b], acc[a][b]);
        __syncthreads();
    }

    const int rowb = (lane >> 4) * 4;
#pragma unroll
    for (int a = 0; a < 4; ++a) {
#pragma unroll
        for (int b = 0; b < 4; ++b) {
            int col = n0 + wn * 64 + b * 16 + fr;
            if (col < Nvalid) {
#pragma unroll
                for (int q = 0; q < 4; ++q) {
                    int row = m0 + wm * 64 + a * 16 + rowb + q;
                    C[(size_t)row * Nvalid + col] = acc[a][b][q];
                }
            }
        }
    }
}

// ---------------------------------------------------------------------------
// prep: dt = softplus(xbcdt[...,1152+h] + dt_bias), a = dt*A, inclusive cumsum
// per (b,c,h) chunk of 256.  Outputs dt[b,c,h,i] and A_cum[b,c,h,i].
// ---------------------------------------------------------------------------
__global__ __launch_bounds__(256) void prep_kernel(
    const float* __restrict__ xbcdt, const float* __restrict__ dt_bias,
    const float* __restrict__ A_log,
    float* __restrict__ dt_out, float* __restrict__ acum_out)
{
    const int h = blockIdx.x, c = blockIdx.y, b = blockIdx.z;
    const int i = threadIdx.x;
    const size_t row = (size_t)b * 4096 + c * 256 + i;
    float z = xbcdt[row * 1184 + 1152 + h] + dt_bias[h];
    float dtv = (z > 20.f) ? z : log1pf(expf(z));
    float Av = -expf(A_log[h]);
    float val = dtv * Av;
    __shared__ float buf[256];
    buf[i] = val;
    __syncthreads();
#pragma unroll
    for (int off = 1; off < 256; off <<= 1) {
        float add = (i >= off) ? buf[i - off] : 0.f;
        __syncthreads();
        val += add;
        buf[i] = val;
        __syncthreads();
    }
    const size_t bch = ((size_t)(b * 16 + c) * 32 + h) * 256;
    dt_out[bch + i]   = dtv;
    acum_out[bch + i] = val;
}

// ---------------------------------------------------------------------------
// xdtT: per (b,c,h) transpose of (x * dt) chunk -> xdtT[b,c,h,p,j] bf16
// ---------------------------------------------------------------------------
__global__ __launch_bounds__(256) void xdtt_kernel(
    const float* __restrict__ xbcdt, const float* __restrict__ dt,
    __bf16* __restrict__ xdtT)
{
    const int h = blockIdx.x, c = blockIdx.y, b = blockIdx.z;
    const size_t bch = ((size_t)(b * 16 + c) * 32 + h);
    __shared__ __bf16 tile[256][33];
    const int t = threadIdx.x;
    for (int idx = t; idx < 256 * 32; idx += 256) {
        int j = idx >> 5, p = idx & 31;
        size_t row = (size_t)b * 4096 + c * 256 + j;
        float x = xbcdt[row * 1184 + h * 32 + p];
        float d = dt[bch * 256 + j];
        tile[j][p] = (__bf16)(x * d);
    }
    __syncthreads();
    for (int idx = t; idx < 32 * 256; idx += 256) {
        int p = idx >> 8, j = idx & 255;
        xdtT[bch * 8192 + p * 256 + j] = tile[j][p];
    }
}

// ---------------------------------------------------------------------------
// CB: per (b,c): CB[i,j] = sum_n C[i,n]*B[j,n]   (256x256, K=64) via MFMA.
// Each block does a 128x128 quadrant.
// ---------------------------------------------------------------------------
__global__ __launch_bounds__(256) void cb_kernel(
    const float* __restrict__ xbcdt, float* __restrict__ CB)
{
    const int nq = blockIdx.x, mq = blockIdx.y, bc = blockIdx.z;
    __shared__ __attribute__((aligned(16))) __bf16 Cs[128 * 72];
    __shared__ __attribute__((aligned(16))) __bf16 Bs2[128 * 72];
    const int t = threadIdx.x;
    const size_t base = (size_t)bc * 256;
    for (int idx = t; idx < 128 * 64; idx += 256) {
        int rr = idx >> 6, n = idx & 63;
        Cs[rr * 72 + n]  = (__bf16)xbcdt[(base + mq * 128 + rr) * 1184 + 1088 + n];
        Bs2[rr * 72 + n] = (__bf16)xbcdt[(base + nq * 128 + rr) * 1184 + 1024 + n];
    }
    __syncthreads();
    const int wave = t >> 6, lane = t & 63;
    const int wm = wave >> 1, wn = wave & 1;
    const int fr = lane & 15, fk = (lane >> 4) * 8;
    f32x4 acc[4][4] = {};
#pragma unroll
    for (int ks = 0; ks < 2; ++ks) {
        bf16x8 af[4], bfv[4];
#pragma unroll
        for (int a = 0; a < 4; ++a)
            af[a] = *(const bf16x8*)&Cs[(wm * 64 + a * 16 + fr) * 72 + ks * 32 + fk];
#pragma unroll
        for (int b = 0; b < 4; ++b)
            bfv[b] = *(const bf16x8*)&Bs2[(wn * 64 + b * 16 + fr) * 72 + ks * 32 + fk];
#pragma unroll
        for (int a = 0; a < 4; ++a)
#pragma unroll
            for (int b = 0; b < 4; ++b)
                acc[a][b] = MFMA16(af[a], bfv[b], acc[a][b]);
    }
    const int rowb = (lane >> 4) * 4;
#pragma unroll
    for (int a = 0; a < 4; ++a)
#pragma unroll
        for (int b = 0; b < 4; ++b)
#pragma unroll
            for (int q = 0; q < 4; ++q) {
                int i = mq * 128 + wm * 64 + a * 16 + rowb + q;
                int j = nq * 128 + wn * 64 + b * 16 + fr;
                CB[(base + i) * 256 + j] = acc[a][b][q];
            }
}

// ---------------------------------------------------------------------------
// states: per (b,c,h): states[p,n] = sum_j xdtT[p,j] * (B[j,n]*exp(alast-ac[j]))
// M=32(p), N=64(n), K=256(j).  Decayed-B^T built in LDS.
// ---------------------------------------------------------------------------
__global__ __launch_bounds__(256) void states_kernel(
    const float* __restrict__ xbcdt, const float* __restrict__ acum,
    const __bf16* __restrict__ xdtT, float* __restrict__ states)
{
    const int h = blockIdx.x, c = blockIdx.y, b = blockIdx.z;
    const size_t bch = ((size_t)(b * 16 + c) * 32 + h);
    __shared__ __attribute__((aligned(16))) __bf16 BdT[64][264];
    const int t = threadIdx.x;
    const float* ac = acum + bch * 256;
    const float alast = ac[255];
    for (int idx = t; idx < 256 * 64; idx += 256) {
        int j = idx >> 6, n = idx & 63;
        float Bv  = xbcdt[((size_t)(b * 16 + c) * 256 + j) * 1184 + 1024 + n];
        float dec = __expf(alast - ac[j]);
        BdT[n][j] = (__bf16)(Bv * dec);
    }
    __syncthreads();
    const int wave = t >> 6, lane = t & 63;
    const int fr = lane & 15, fk = (lane >> 4) * 8;
    const int mt  = wave >> 1;
    const int ntb = (wave & 1) * 2;
    f32x4 acc[2] = {};
    const __bf16* xrow = xdtT + bch * 8192;
#pragma unroll
    for (int ks = 0; ks < 8; ++ks) {
        bf16x8 af = *(const bf16x8*)&xrow[(mt * 16 + fr) * 256 + ks * 32 + fk];
#pragma unroll
        for (int nb = 0; nb < 2; ++nb) {
            bf16x8 bfv = *(const bf16x8*)&BdT[(ntb + nb) * 16 + fr][ks * 32 + fk];
            acc[nb] = MFMA16(af, bfv, acc[nb]);
        }
    }
    const int rowb = (lane >> 4) * 4;
#pragma unroll
    for (int nb = 0; nb < 2; ++nb)
#pragma unroll
        for (int q = 0; q < 4; ++q) {
            int p = mt * 16 + rowb + q;
            int n = (ntb + nb) * 16 + fr;
            states[bch * 2048 + p * 64 + n] = acc[nb][q];
        }
}

// ---------------------------------------------------------------------------
// scan: prev[b,0] = 0 ; prev[b,c] = prev[b,c-1]*exp(acum_last[c-1]) + states[c-1]
// One thread per (b,h,p,n).
// ---------------------------------------------------------------------------
__global__ void scan_kernel(const float* __restrict__ states,
                            const float* __restrict__ acum,
                            float* __restrict__ prev)
{
    int t = blockIdx.x * 256 + threadIdx.x;
    int n = t & 63, p = (t >> 6) & 31, h = (t >> 11) & 31, b = t >> 16;
    float s = 0.f;
    for (int c = 0; c < 16; ++c) {
        size_t bch = ((size_t)(b * 16 + c) * 32 + h);
        size_t off = bch * 2048 + (size_t)p * 64 + n;
        prev[off] = s;
        float dec = __expf(acum[bch * 256 + 255]);
        s = s * dec + states[off];
    }
}

// ---------------------------------------------------------------------------
// y: per (b,c,h,quarter): build G[i,j] = CB[i,j]*exp(ac[i]-ac[j]) (j<=i) in LDS
// (bf16), Y = G @ xdtT^T + (C*exp(ac[i])) @ prev^T + x*D, write bf16 y.
// M=64 rows per block; N=32(p); K=256 then K=64.
// ---------------------------------------------------------------------------
__global__ __launch_bounds__(256) void y_kernel(
    const float* __restrict__ xbcdt, const float* __restrict__ CBp,
    const float* __restrict__ acum, const __bf16* __restrict__ xdtT,
    const float* __restrict__ prev, const float* __restrict__ Dp,
    __bf16* __restrict__ ybf)
{
    const int h = blockIdx.x >> 2, quarter = blockIdx.x & 3;
    const int c = blockIdx.y, b = blockIdx.z;
    const size_t bc  = (size_t)b * 16 + c;
    const size_t bch = bc * 32 + h;
    __shared__ __attribute__((aligned(16))) __bf16 G[64][264];
    __shared__ float ash[256];
    const int t = threadIdx.x;
    ash[t] = acum[bch * 256 + t];
    __syncthreads();
    const int i0 = quarter * 64;
    for (int idx = t; idx < 64 * 256; idx += 256) {
        int ii = idx >> 8, j = idx & 255;
        int i = i0 + ii;
        float g = 0.f;
        if (j <= i) g = CBp[(bc * 256 + i) * 256 + j] * __expf(ash[i] - ash[j]);
        G[ii][j] = (__bf16)g;
    }
    __syncthreads();
    const int wave = t >> 6, lane = t & 63;
    const int fr = lane & 15, fk = (lane >> 4) * 8;
    f32x4 acc[2] = {};
    const __bf16* xrow = xdtT + bch * 8192;
#pragma unroll
    for (int ks = 0; ks < 8; ++ks) {
        bf16x8 af = *(const bf16x8*)&G[wave * 16 + fr][ks * 32 + fk];
#pragma unroll
        for (int nb = 0; nb < 2; ++nb) {
            bf16x8 bfv = *(const bf16x8*)&xrow[(nb * 16 + fr) * 256 + ks * 32 + fk];
            acc[nb] = MFMA16(af, bfv, acc[nb]);
        }
    }
    // Y_off: A = C[i,n]*exp(ac[i]) (K=64), B = prev[p,n]
    const float* prow = prev + bch * 2048;
#pragma unroll
    for (int ks = 0; ks < 2; ++ks) {
        int i = i0 + wave * 16 + fr;
        float e = __expf(ash[i]);
        const float* cp = &xbcdt[(bc * 256 + i) * 1184 + 1088 + ks * 32 + fk];
        bf16x8 af;
#pragma unroll
        for (int q = 0; q < 8; ++q) af[q] = (__bf16)(cp[q] * e);
#pragma unroll
        for (int nb = 0; nb < 2; ++nb) {
            const float* pp = &prow[(nb * 16 + fr) * 64 + ks * 32 + fk];
            bf16x8 bfv;
#pragma unroll
            for (int q = 0; q < 8; ++q) bfv[q] = (__bf16)pp[q];
            acc[nb] = MFMA16(af, bfv, acc[nb]);
        }
    }
    const float Dv = Dp[h];
    const int rowb = (lane >> 4) * 4;
#pragma unroll
    for (int nb = 0; nb < 2; ++nb)
#pragma unroll
        for (int q = 0; q < 4; ++q) {
            int i = i0 + wave * 16 + rowb + q;
            int p = nb * 16 + fr;
            size_t row = bc * 256 + i;
            float x = xbcdt[row * 1184 + h * 32 + p];
            ybf[row * 1024 + h * 32 + p] = (__bf16)(acc[nb][q] + x * Dv);
        }
}

// ---------------------------------------------------------------------------
// launch
// ---------------------------------------------------------------------------
extern "C" void kernel_launch(void* const* d_in, const int* in_sizes, int n_in,
                              void* d_out, int out_size, void* d_ws, size_t ws_size,
                              hipStream_t stream)
{
    (void)in_sizes; (void)n_in; (void)out_size;
    const float* u       = (const float*)d_in[0];
    const float* W_in    = (const float*)d_in[1];
    const float* dt_bias = (const float*)d_in[2];
    const float* A_log   = (const float*)d_in[3];
    const float* Dp      = (const float*)d_in[4];
    const float* W_out   = (const float*)d_in[5];
    float* out = (float*)d_out;

    if (ws_size < 104136704) return;  // need ~104 MB scratch

    char* ws = (char*)d_ws;
    __bf16* u_bf    = (__bf16*)(ws);                  // 16,777,216 B (reused as ybf)
    __bf16* win_bf  = (__bf16*)(ws + 16777216);       //  2,424,832 B
    __bf16* wout_bf = (__bf16*)(ws + 19202048);       //  2,097,152 B
    float*  xbcdt   = (float*) (ws + 21299200);       // 38,797,312 B
    float*  dtb     = (float*) (ws + 60096512);       //  1,048,576 B
    float*  acum    = (float*) (ws + 61145088);       //  1,048,576 B
    __bf16* xdtT    = (__bf16*)(ws + 62193664);       // 16,777,216 B
    float*  CBp     = (float*) (ws + 78970880);       //  8,388,608 B
    float*  states  = (float*) (ws + 87359488);       //  8,388,608 B
    float*  prev    = (float*) (ws + 95748096);       //  8,388,608 B

    cvt_f32_bf16<<<8192, 256, 0, stream>>>(u, u_bf, 8388608);
    cvt_f32_bf16<<<1184, 256, 0, stream>>>(W_in, win_bf, 1212416);
    cvt_f32_bf16<<<1024, 256, 0, stream>>>(W_out, wout_bf, 1048576);

    gemm_bt<<<dim3(10, 64), 256, 0, stream>>>(u_bf, win_bf, xbcdt, 1024, 1184, 1184);

    prep_kernel<<<dim3(32, 16, 2), 256, 0, stream>>>(xbcdt, dt_bias, A_log, dtb, acum);
    xdtt_kernel<<<dim3(32, 16, 2), 256, 0, stream>>>(xbcdt, dtb, xdtT);
    cb_kernel<<<dim3(2, 2, 32), 256, 0, stream>>>(xbcdt, CBp);
    states_kernel<<<dim3(32, 16, 2), 256, 0, stream>>>(xbcdt, acum, xdtT, states);
    scan_kernel<<<512, 256, 0, stream>>>(states, acum, prev);

    __bf16* ybf = u_bf;  // u_bf dead after gemm1
    y_kernel<<<dim3(128, 16, 2), 256, 0, stream>>>(xbcdt, CBp, acum, xdtT, prev, Dp, ybf);

    gemm_bt<<<dim3(8, 64), 256, 0, stream>>>(ybf, wout_bf, out, 1024, 1024, 1024);
}

// Round 2
// 331.206 us; speedup vs baseline: 1.0619x; 1.0619x over previous
//
#include <hip/hip_runtime.h>
#include <hip/hip_bf16.h>
#include <stdint.h>

// ---------------------------------------------------------------------------
// SSD (Mamba-2 chunked scan) for B=2, L=4096, DM=1024, NH=32, HD=32, DS=64,
// CS=256.  All heavy matmuls in bf16 MFMA (16x16x32), fp32 accumulation.
// R2: fused S=C@B^T into y_kernel (no CB materialization), Y_off folded into
// the same MFMA contraction (K=320), m97-style global_load_lds GEMMs.
// ---------------------------------------------------------------------------

typedef __bf16 bf16x8 __attribute__((ext_vector_type(8)));
typedef __bf16 bf16x4 __attribute__((ext_vector_type(4)));
typedef float  f32x4  __attribute__((ext_vector_type(4)));

#define MFMA16(a, b, c) __builtin_amdgcn_mfma_f32_16x16x32_bf16((a), (b), (c), 0, 0, 0)

__device__ __forceinline__ void async_copy16(const __bf16* g, __bf16* l) {
    __builtin_amdgcn_global_load_lds((const __attribute__((address_space(1))) void*)g,
                                     (__attribute__((address_space(3))) void*)l,
                                     16, 0, 0);
}

// ---------------------------------------------------------------------------
// fp32 -> bf16 convert (4 elements / thread)
// ---------------------------------------------------------------------------
__global__ void cvt_f32_bf16(const float* __restrict__ in, __bf16* __restrict__ out, int n) {
    int i = (blockIdx.x * 256 + threadIdx.x) * 4;
    if (i + 3 < n) {
        float4 v = *(const float4*)(in + i);
        bf16x4 o;
        o[0] = (__bf16)v.x; o[1] = (__bf16)v.y; o[2] = (__bf16)v.z; o[3] = (__bf16)v.w;
        *(bf16x4*)(out + i) = o;
    } else {
        for (int k = i; k < n; ++k) out[k] = (__bf16)in[k];
    }
}

// ---------------------------------------------------------------------------
// GEMM: C[M x Nvalid] (fp32) = A[M x K] (bf16) @ Bt[Nrows x K]^T (bf16)
// 128x128 block tile, BK=32, m97-style global_load_lds width-16 staging.
// ---------------------------------------------------------------------------
__global__ __launch_bounds__(256) void gemm_bt(
    const __bf16* __restrict__ A, const __bf16* __restrict__ Bt,
    float* __restrict__ C, int K, int Nrows, int Nvalid)
{
    __shared__ __attribute__((aligned(16))) __bf16 As[128 * 32];
    __shared__ __attribute__((aligned(16))) __bf16 Bs[128 * 32];
    const int tid = threadIdx.x;
    const int m0 = blockIdx.y * 128;
    const int n0 = blockIdx.x * 128;
    const int r  = tid >> 2;
    const int c8 = (tid & 3) * 8;
    const int wave = tid >> 6, lane = tid & 63;
    const int wm = wave >> 1, wn = wave & 1;
    const int fr = lane & 15, fk = (lane >> 4) * 8;

    const int br0 = min(n0 + r, Nrows - 1);
    const int br1 = min(n0 + 64 + r, Nrows - 1);
    const __bf16* a0 = A + (size_t)(m0 + r) * K + c8;
    const __bf16* a1 = A + (size_t)(m0 + 64 + r) * K + c8;
    const __bf16* b0 = Bt + (size_t)br0 * K + c8;
    const __bf16* b1 = Bt + (size_t)br1 * K + c8;
    __bf16* asb0 = As + wave * 512;          // wave-uniform LDS bases (lane*16B auto)
    __bf16* asb1 = As + 2048 + wave * 512;
    __bf16* bsb0 = Bs + wave * 512;
    __bf16* bsb1 = Bs + 2048 + wave * 512;

    f32x4 acc[4][4] = {};

    for (int kt = 0; kt < K; kt += 32) {
        async_copy16(a0 + kt, asb0);
        async_copy16(a1 + kt, asb1);
        async_copy16(b0 + kt, bsb0);
        async_copy16(b1 + kt, bsb1);
        __syncthreads();
        bf16x8 af[4], bfv[4];
#pragma unroll
        for (int a = 0; a < 4; ++a)
            af[a] = *(const bf16x8*)&As[(wm * 64 + a * 16 + fr) * 32 + fk];
#pragma unroll
        for (int b = 0; b < 4; ++b)
            bfv[b] = *(const bf16x8*)&Bs[(wn * 64 + b * 16 + fr) * 32 + fk];
#pragma unroll
        for (int a = 0; a < 4; ++a)
#pragma unroll
            for (int b = 0; b < 4; ++b)
                acc[a][b] = MFMA16(af[a], bfv[b], acc[a][b]);
        __syncthreads();
    }

    const int rowb = (lane >> 4) * 4;
#pragma unroll
    for (int a = 0; a < 4; ++a) {
#pragma unroll
        for (int b = 0; b < 4; ++b) {
            int col = n0 + wn * 64 + b * 16 + fr;
            if (col < Nvalid) {
#pragma unroll
                for (int q = 0; q < 4; ++q) {
                    int row = m0 + wm * 64 + a * 16 + rowb + q;
                    C[(size_t)row * Nvalid + col] = acc[a][b][q];
                }
            }
        }
    }
}

// ---------------------------------------------------------------------------
// prep: dt = softplus(xbcdt[...,1152+h] + dt_bias), a = dt*A, inclusive cumsum
// ---------------------------------------------------------------------------
__global__ __launch_bounds__(256) void prep_kernel(
    const float* __restrict__ xbcdt, const float* __restrict__ dt_bias,
    const float* __restrict__ A_log,
    float* __restrict__ dt_out, float* __restrict__ acum_out)
{
    const int h = blockIdx.x, c = blockIdx.y, b = blockIdx.z;
    const int i = threadIdx.x;
    const size_t row = (size_t)b * 4096 + c * 256 + i;
    float z = xbcdt[row * 1184 + 1152 + h] + dt_bias[h];
    float dtv = (z > 20.f) ? z : log1pf(expf(z));
    float Av = -expf(A_log[h]);
    float val = dtv * Av;
    __shared__ float buf[256];
    buf[i] = val;
    __syncthreads();
#pragma unroll
    for (int off = 1; off < 256; off <<= 1) {
        float add = (i >= off) ? buf[i - off] : 0.f;
        __syncthreads();
        val += add;
        buf[i] = val;
        __syncthreads();
    }
    const size_t bch = ((size_t)(b * 16 + c) * 32 + h) * 256;
    dt_out[bch + i]   = dtv;
    acum_out[bch + i] = val;
}

// ---------------------------------------------------------------------------
// bc_cvt: extract B,C columns of xbcdt -> bf16 buffers Bbf/Cbf [row][64]
// ---------------------------------------------------------------------------
__global__ void bc_cvt(const float* __restrict__ xbcdt,
                       __bf16* __restrict__ Bbf, __bf16* __restrict__ Cbf)
{
    int t = blockIdx.x * 256 + threadIdx.x;   // 8192 rows * 128 cols
    int row = t >> 7, col = t & 127;
    float v = xbcdt[(size_t)row * 1184 + 1024 + col];
    if (col < 64) Bbf[row * 64 + col] = (__bf16)v;
    else          Cbf[row * 64 + col - 64] = (__bf16)v;
}

// ---------------------------------------------------------------------------
// xdtT: per (b,c,h) transpose of (x * dt) chunk -> xdtT[b,c,h,p,j] bf16
// ---------------------------------------------------------------------------
__global__ __launch_bounds__(256) void xdtt_kernel(
    const float* __restrict__ xbcdt, const float* __restrict__ dt,
    __bf16* __restrict__ xdtT)
{
    const int h = blockIdx.x, c = blockIdx.y, b = blockIdx.z;
    const size_t bch = ((size_t)(b * 16 + c) * 32 + h);
    __shared__ __bf16 tile[256][33];
    const int t = threadIdx.x;
    for (int idx = t; idx < 256 * 32; idx += 256) {
        int j = idx >> 5, p = idx & 31;
        size_t row = (size_t)b * 4096 + c * 256 + j;
        float x = xbcdt[row * 1184 + h * 32 + p];
        float d = dt[bch * 256 + j];
        tile[j][p] = (__bf16)(x * d);
    }
    __syncthreads();
    for (int idx = t; idx < 32 * 256; idx += 256) {
        int p = idx >> 8, j = idx & 255;
        xdtT[bch * 8192 + p * 256 + j] = tile[j][p];
    }
}

// ---------------------------------------------------------------------------
// states: per (b,c,h): states[p,n] = sum_j xdtT[p,j] * (B[j,n]*exp(alast-ac[j]))
// ---------------------------------------------------------------------------
__global__ __launch_bounds__(256) void states_kernel(
    const __bf16* __restrict__ Bbf, const float* __restrict__ acum,
    const __bf16* __restrict__ xdtT, float* __restrict__ states)
{
    const int h = blockIdx.x, c = blockIdx.y, b = blockIdx.z;
    const size_t bch = ((size_t)(b * 16 + c) * 32 + h);
    __shared__ __attribute__((aligned(16))) __bf16 BdT[64][264];
    const int t = threadIdx.x;
    const float* ac = acum + bch * 256;
    const float alast = ac[255];
    for (int idx = t; idx < 256 * 64; idx += 256) {
        int j = idx >> 6, n = idx & 63;
        float Bv  = (float)Bbf[((size_t)(b * 16 + c) * 256 + j) * 64 + n];
        float dec = __expf(alast - ac[j]);
        BdT[n][j] = (__bf16)(Bv * dec);
    }
    __syncthreads();
    const int wave = t >> 6, lane = t & 63;
    const int fr = lane & 15, fk = (lane >> 4) * 8;
    const int mt  = wave >> 1;
    const int ntb = (wave & 1) * 2;
    f32x4 acc[2] = {};
    const __bf16* xrow = xdtT + bch * 8192;
#pragma unroll
    for (int ks = 0; ks < 8; ++ks) {
        bf16x8 af = *(const bf16x8*)&xrow[(mt * 16 + fr) * 256 + ks * 32 + fk];
#pragma unroll
        for (int nb = 0; nb < 2; ++nb) {
            bf16x8 bfv = *(const bf16x8*)&BdT[(ntb + nb) * 16 + fr][ks * 32 + fk];
            acc[nb] = MFMA16(af, bfv, acc[nb]);
        }
    }
    const int rowb = (lane >> 4) * 4;
#pragma unroll
    for (int nb = 0; nb < 2; ++nb)
#pragma unroll
        for (int q = 0; q < 4; ++q) {
            int p = mt * 16 + rowb + q;
            int n = (ntb + nb) * 16 + fr;
            states[bch * 2048 + p * 64 + n] = acc[nb][q];
        }
}

// ---------------------------------------------------------------------------
// scan: prev[b,0]=0 ; prev[b,c] = prev[b,c-1]*exp(acum_last[c-1]) + states[c-1]
// writes bf16 (consumed only by y_kernel MFMA).
// ---------------------------------------------------------------------------
__global__ void scan_kernel(const float* __restrict__ states,
                            const float* __restrict__ acum,
                            __bf16* __restrict__ prevbf)
{
    int t = blockIdx.x * 256 + threadIdx.x;
    int n = t & 63, p = (t >> 6) & 31, h = (t >> 11) & 31, b = t >> 16;
    float s = 0.f;
    for (int c = 0; c < 16; ++c) {
        size_t bch = ((size_t)(b * 16 + c) * 32 + h);
        size_t off = bch * 2048 + (size_t)p * 64 + n;
        prevbf[off] = (__bf16)s;
        float dec = __expf(acum[bch * 256 + 255]);
        s = s * dec + states[off];
    }
}

// ---------------------------------------------------------------------------
// y: per (b,c,h,quarter):
//   Phase 1: S = C_quad @ B^T via MFMA (K=64), G[i][j] = masked decayed S (bf16
//            in LDS); G cols 256..319 = C[i,n]*exp(a_i).
//   Phase 2: Y = G @ [xdtT ; prev]^T  (one K=320 MFMA chain), + x*D, store bf16.
// ---------------------------------------------------------------------------
__global__ __launch_bounds__(256) void y_kernel(
    const __bf16* __restrict__ Bbf, const __bf16* __restrict__ Cbf,
    const float* __restrict__ acum, const __bf16* __restrict__ xdtT,
    const __bf16* __restrict__ prevbf, const float* __restrict__ xbcdt,
    const float* __restrict__ Dp, __bf16* __restrict__ ybf)
{
    const int q4 = blockIdx.x & 3, h = blockIdx.x >> 2;
    const int c = blockIdx.y, b = blockIdx.z;
    const size_t bc  = (size_t)b * 16 + c;
    const size_t bch = bc * 32 + h;
    __shared__ __attribute__((aligned(16))) __bf16 G[64][328];  // 320 cols + 8 pad
    __shared__ float ash[256];
    const int t = threadIdx.x;
    ash[t] = acum[bch * 256 + t];
    const int wave = t >> 6, lane = t & 63;
    const int fr = lane & 15, quad = lane >> 4, fk = quad * 8;
    const int i0 = q4 * 64;
    __syncthreads();

    // ---- Phase 1: S = C_quad @ B^T, decay+mask -> G[0..63][0..255]
    const __bf16* Crow = Cbf + ((size_t)(bc * 256) + i0 + wave * 16 + fr) * 64;
    bf16x8 caf0 = *(const bf16x8*)(Crow + fk);
    bf16x8 caf1 = *(const bf16x8*)(Crow + 32 + fk);
    const int iql = wave * 16 + quad * 4;   // C/D-layout local row base
    float ai[4];
#pragma unroll
    for (int qq = 0; qq < 4; ++qq) ai[qq] = ash[i0 + iql + qq];
#pragma unroll
    for (int nt = 0; nt < 16; ++nt) {
        const __bf16* Brow = Bbf + ((size_t)(bc * 256) + nt * 16 + fr) * 64;
        f32x4 acc = {};
        acc = MFMA16(caf0, *(const bf16x8*)(Brow + fk), acc);
        acc = MFMA16(caf1, *(const bf16x8*)(Brow + 32 + fk), acc);
        int j = nt * 16 + fr;
        float aj = ash[j];
#pragma unroll
        for (int qq = 0; qq < 4; ++qq) {
            int il = iql + qq;
            float g = (j <= i0 + il) ? acc[qq] * __expf(ai[qq] - aj) : 0.f;
            G[il][j] = (__bf16)g;
        }
    }
    // ---- G cols 256..319 = C[i,n] * exp(a_i)
    for (int idx = t; idx < 64 * 64; idx += 256) {
        int ii = idx >> 6, n = idx & 63;
        float e = __expf(ash[i0 + ii]);
        G[ii][256 + n] = (__bf16)((float)Cbf[((size_t)(bc * 256) + i0 + ii) * 64 + n] * e);
    }
    __syncthreads();

    // ---- Phase 2: Y = G @ [xdtT ; prev]^T   (K = 320)
    f32x4 acc2[2] = {};
    const __bf16* Grow = &G[wave * 16 + fr][0];
    const __bf16* xrow = xdtT + bch * 8192;
    const __bf16* prow = prevbf + bch * 2048;
#pragma unroll
    for (int ks = 0; ks < 8; ++ks) {
        bf16x8 af = *(const bf16x8*)(Grow + ks * 32 + fk);
#pragma unroll
        for (int nb = 0; nb < 2; ++nb) {
            bf16x8 bfv = *(const bf16x8*)(xrow + (nb * 16 + fr) * 256 + ks * 32 + fk);
            acc2[nb] = MFMA16(af, bfv, acc2[nb]);
        }
    }
#pragma unroll
    for (int ks = 8; ks < 10; ++ks) {
        bf16x8 af = *(const bf16x8*)(Grow + ks * 32 + fk);
#pragma unroll
        for (int nb = 0; nb < 2; ++nb) {
            bf16x8 bfv = *(const bf16x8*)(prow + (nb * 16 + fr) * 64 + (ks - 8) * 32 + fk);
            acc2[nb] = MFMA16(af, bfv, acc2[nb]);
        }
    }

    const float Dv = Dp[h];
    const int rowb = quad * 4;
#pragma unroll
    for (int nb = 0; nb < 2; ++nb)
#pragma unroll
        for (int qq = 0; qq < 4; ++qq) {
            int i = i0 + wave * 16 + rowb + qq;
            int p = nb * 16 + fr;
            size_t row = bc * 256 + i;
            float x = xbcdt[row * 1184 + h * 32 + p];
            ybf[row * 1024 + h * 32 + p] = (__bf16)(acc2[nb][qq] + x * Dv);
        }
}

// ---------------------------------------------------------------------------
// launch
// ---------------------------------------------------------------------------
extern "C" void kernel_launch(void* const* d_in, const int* in_sizes, int n_in,
                              void* d_out, int out_size, void* d_ws, size_t ws_size,
                              hipStream_t stream)
{
    (void)in_sizes; (void)n_in; (void)out_size;
    const float* u       = (const float*)d_in[0];
    const float* W_in    = (const float*)d_in[1];
    const float* dt_bias = (const float*)d_in[2];
    const float* A_log   = (const float*)d_in[3];
    const float* Dp      = (const float*)d_in[4];
    const float* W_out   = (const float*)d_in[5];
    float* out = (float*)d_out;

    if (ws_size < 93650944) return;

    char* ws = (char*)d_ws;
    __bf16* u_bf    = (__bf16*)(ws);                  // 16,777,216 (reused as ybf)
    __bf16* win_bf  = (__bf16*)(ws + 16777216);       //  2,424,832
    __bf16* wout_bf = (__bf16*)(ws + 19202048);       //  2,097,152
    float*  xbcdt   = (float*) (ws + 21299200);       // 38,797,312
    float*  dtb     = (float*) (ws + 60096512);       //  1,048,576
    float*  acum    = (float*) (ws + 61145088);       //  1,048,576
    __bf16* xdtT    = (__bf16*)(ws + 62193664);       // 16,777,216
    float*  states  = (float*) (ws + 78970880);       //  8,388,608
    __bf16* prevbf  = (__bf16*)(ws + 87359488);       //  4,194,304
    __bf16* Bbf     = (__bf16*)(ws + 91553792);       //  1,048,576
    __bf16* Cbf     = (__bf16*)(ws + 92602368);       //  1,048,576

    cvt_f32_bf16<<<8192, 256, 0, stream>>>(u, u_bf, 8388608);
    cvt_f32_bf16<<<1184, 256, 0, stream>>>(W_in, win_bf, 1212416);
    cvt_f32_bf16<<<1024, 256, 0, stream>>>(W_out, wout_bf, 1048576);

    gemm_bt<<<dim3(10, 64), 256, 0, stream>>>(u_bf, win_bf, xbcdt, 1024, 1184, 1184);

    prep_kernel<<<dim3(32, 16, 2), 256, 0, stream>>>(xbcdt, dt_bias, A_log, dtb, acum);
    bc_cvt<<<4096, 256, 0, stream>>>(xbcdt, Bbf, Cbf);
    xdtt_kernel<<<dim3(32, 16, 2), 256, 0, stream>>>(xbcdt, dtb, xdtT);
    states_kernel<<<dim3(32, 16, 2), 256, 0, stream>>>(Bbf, acum, xdtT, states);
    scan_kernel<<<512, 256, 0, stream>>>(states, acum, prevbf);

    __bf16* ybf = u_bf;  // u_bf dead after gemm1
    y_kernel<<<dim3(128, 16, 2), 256, 0, stream>>>(Bbf, Cbf, acum, xdtT, prevbf,
                                                   xbcdt, Dp, ybf);

    gemm_bt<<<dim3(8, 64), 256, 0, stream>>>(ybf, wout_bf, out, 1024, 1024, 1024);
}

// Round 3
// 232.282 us; speedup vs baseline: 1.5142x; 1.4259x over previous
//
#include <hip/hip_runtime.h>
#include <hip/hip_bf16.h>
#include <stdint.h>

// ---------------------------------------------------------------------------
// SSD (Mamba-2 chunked scan) B=2, L=4096, DM=1024, NH=32, HD=32, DS=64, CS=256
// R3: y_kernel restructured: block=(b,c,h), async LDS staging (swizzled),
// wave-private G scratch, single barrier, off-term via in-register B-frags.
// ---------------------------------------------------------------------------

typedef __bf16 bf16x8 __attribute__((ext_vector_type(8)));
typedef __bf16 bf16x4 __attribute__((ext_vector_type(4)));
typedef float  f32x4  __attribute__((ext_vector_type(4)));

#define MFMA16(a, b, c) __builtin_amdgcn_mfma_f32_16x16x32_bf16((a), (b), (c), 0, 0, 0)

__device__ __forceinline__ void async_copy16(const __bf16* g, __bf16* l) {
    __builtin_amdgcn_global_load_lds((const __attribute__((address_space(1))) void*)g,
                                     (__attribute__((address_space(3))) void*)l,
                                     16, 0, 0);
}

// ---------------------------------------------------------------------------
__global__ void cvt_f32_bf16(const float* __restrict__ in, __bf16* __restrict__ out, int n) {
    int i = (blockIdx.x * 256 + threadIdx.x) * 4;
    if (i + 3 < n) {
        float4 v = *(const float4*)(in + i);
        bf16x4 o;
        o[0] = (__bf16)v.x; o[1] = (__bf16)v.y; o[2] = (__bf16)v.z; o[3] = (__bf16)v.w;
        *(bf16x4*)(out + i) = o;
    } else {
        for (int k = i; k < n; ++k) out[k] = (__bf16)in[k];
    }
}

// ---------------------------------------------------------------------------
// GEMM: C[M x Nvalid] = A[M x K] @ Bt[Nrows x K]^T  (128x128 tile, async LDS)
// ---------------------------------------------------------------------------
__global__ __launch_bounds__(256) void gemm_bt(
    const __bf16* __restrict__ A, const __bf16* __restrict__ Bt,
    float* __restrict__ C, int K, int Nrows, int Nvalid)
{
    __shared__ __attribute__((aligned(16))) __bf16 As[128 * 32];
    __shared__ __attribute__((aligned(16))) __bf16 Bs[128 * 32];
    const int tid = threadIdx.x;
    const int m0 = blockIdx.y * 128;
    const int n0 = blockIdx.x * 128;
    const int r  = tid >> 2;
    const int c8 = (tid & 3) * 8;
    const int wave = tid >> 6, lane = tid & 63;
    const int wm = wave >> 1, wn = wave & 1;
    const int fr = lane & 15, fk = (lane >> 4) * 8;

    const int br0 = min(n0 + r, Nrows - 1);
    const int br1 = min(n0 + 64 + r, Nrows - 1);
    const __bf16* a0 = A + (size_t)(m0 + r) * K + c8;
    const __bf16* a1 = A + (size_t)(m0 + 64 + r) * K + c8;
    const __bf16* b0 = Bt + (size_t)br0 * K + c8;
    const __bf16* b1 = Bt + (size_t)br1 * K + c8;
    __bf16* asb0 = As + wave * 512;
    __bf16* asb1 = As + 2048 + wave * 512;
    __bf16* bsb0 = Bs + wave * 512;
    __bf16* bsb1 = Bs + 2048 + wave * 512;

    f32x4 acc[4][4] = {};

    for (int kt = 0; kt < K; kt += 32) {
        async_copy16(a0 + kt, asb0);
        async_copy16(a1 + kt, asb1);
        async_copy16(b0 + kt, bsb0);
        async_copy16(b1 + kt, bsb1);
        __syncthreads();
        bf16x8 af[4], bfv[4];
#pragma unroll
        for (int a = 0; a < 4; ++a)
            af[a] = *(const bf16x8*)&As[(wm * 64 + a * 16 + fr) * 32 + fk];
#pragma unroll
        for (int b = 0; b < 4; ++b)
            bfv[b] = *(const bf16x8*)&Bs[(wn * 64 + b * 16 + fr) * 32 + fk];
#pragma unroll
        for (int a = 0; a < 4; ++a)
#pragma unroll
            for (int b = 0; b < 4; ++b)
                acc[a][b] = MFMA16(af[a], bfv[b], acc[a][b]);
        __syncthreads();
    }

    const int rowb = (lane >> 4) * 4;
#pragma unroll
    for (int a = 0; a < 4; ++a) {
#pragma unroll
        for (int b = 0; b < 4; ++b) {
            int col = n0 + wn * 64 + b * 16 + fr;
            if (col < Nvalid) {
#pragma unroll
                for (int q = 0; q < 4; ++q) {
                    int row = m0 + wm * 64 + a * 16 + rowb + q;
                    C[(size_t)row * Nvalid + col] = acc[a][b][q];
                }
            }
        }
    }
}

// ---------------------------------------------------------------------------
// prep: dt = softplus(..), a = dt*A, inclusive cumsum per (b,c,h)
// ---------------------------------------------------------------------------
__global__ __launch_bounds__(256) void prep_kernel(
    const float* __restrict__ xbcdt, const float* __restrict__ dt_bias,
    const float* __restrict__ A_log,
    float* __restrict__ dt_out, float* __restrict__ acum_out)
{
    const int h = blockIdx.x, c = blockIdx.y, b = blockIdx.z;
    const int i = threadIdx.x;
    const size_t row = (size_t)b * 4096 + c * 256 + i;
    float z = xbcdt[row * 1184 + 1152 + h] + dt_bias[h];
    float dtv = (z > 20.f) ? z : log1pf(expf(z));
    float Av = -expf(A_log[h]);
    float val = dtv * Av;
    __shared__ float buf[256];
    buf[i] = val;
    __syncthreads();
#pragma unroll
    for (int off = 1; off < 256; off <<= 1) {
        float add = (i >= off) ? buf[i - off] : 0.f;
        __syncthreads();
        val += add;
        buf[i] = val;
        __syncthreads();
    }
    const size_t bch = ((size_t)(b * 16 + c) * 32 + h) * 256;
    dt_out[bch + i]   = dtv;
    acum_out[bch + i] = val;
}

// ---------------------------------------------------------------------------
// bc_cvt: extract B,C cols of xbcdt -> bf16 Bbf/Cbf [row][64]
// ---------------------------------------------------------------------------
__global__ void bc_cvt(const float* __restrict__ xbcdt,
                       __bf16* __restrict__ Bbf, __bf16* __restrict__ Cbf)
{
    int t = blockIdx.x * 256 + threadIdx.x;
    int row = t >> 7, col = t & 127;
    float v = xbcdt[(size_t)row * 1184 + 1024 + col];
    if (col < 64) Bbf[row * 64 + col] = (__bf16)v;
    else          Cbf[row * 64 + col - 64] = (__bf16)v;
}

// ---------------------------------------------------------------------------
// xdtT: per (b,c,h) transpose of (x*dt) chunk -> xdtT[b,c,h,p,j] bf16
// ---------------------------------------------------------------------------
__global__ __launch_bounds__(256) void xdtt_kernel(
    const float* __restrict__ xbcdt, const float* __restrict__ dt,
    __bf16* __restrict__ xdtT)
{
    const int h = blockIdx.x, c = blockIdx.y, b = blockIdx.z;
    const size_t bch = ((size_t)(b * 16 + c) * 32 + h);
    __shared__ __bf16 tile[256][33];
    __shared__ float dts[256];
    const int t = threadIdx.x;
    dts[t] = dt[bch * 256 + t];
    __syncthreads();
#pragma unroll
    for (int it = 0; it < 8; ++it) {
        int id = it * 256 + t;
        int j = id >> 3, pg = id & 7;
        float4 v = *(const float4*)&xbcdt[((size_t)(b * 16 + c) * 256 + j) * 1184 + h * 32 + pg * 4];
        float d = dts[j];
        tile[j][pg * 4 + 0] = (__bf16)(v.x * d);
        tile[j][pg * 4 + 1] = (__bf16)(v.y * d);
        tile[j][pg * 4 + 2] = (__bf16)(v.z * d);
        tile[j][pg * 4 + 3] = (__bf16)(v.w * d);
    }
    __syncthreads();
#pragma unroll
    for (int it = 0; it < 4; ++it) {
        int id = it * 256 + t;
        int p = id >> 5, jg = id & 31;
        bf16x8 o;
#pragma unroll
        for (int e = 0; e < 8; ++e) o[e] = tile[jg * 8 + e][p];
        *(bf16x8*)&xdtT[bch * 8192 + p * 256 + jg * 8] = o;
    }
}

// ---------------------------------------------------------------------------
// states: per (b,c,h): states[p,n] = sum_j xdt[p,j] * B[j,n] * exp(alast-a_j)
// async-staged B, LDS decs, MFMA.
// ---------------------------------------------------------------------------
__global__ __launch_bounds__(256) void states_kernel(
    const __bf16* __restrict__ Bbf, const float* __restrict__ acum,
    const __bf16* __restrict__ xdtT, float* __restrict__ states)
{
    const int h = blockIdx.x, c = blockIdx.y, b = blockIdx.z;
    const size_t bc = (size_t)b * 16 + c;
    const size_t bch = bc * 32 + h;
    __shared__ __attribute__((aligned(16))) __bf16 Bsh[256 * 64];
    __shared__ __attribute__((aligned(16))) __bf16 BdT[64][264];
    __shared__ float decs[256];
    __shared__ float alast_sh;
    const int t = threadIdx.x, wave = t >> 6, lane = t & 63;

    const __bf16* Bsrc = Bbf + bc * 16384;
#pragma unroll
    for (int cc = 0; cc < 8; ++cc) {
        int s = wave * 8 + cc;
        int row = s * 8 + (lane >> 3);
        async_copy16(Bsrc + row * 64 + (lane & 7) * 8, Bsh + s * 512);
    }
    float a = acum[bch * 256 + t];
    if (t == 255) alast_sh = a;
    __syncthreads();
    decs[t] = __expf(alast_sh - a);
    __syncthreads();
    for (int idx = t; idx < 256 * 64; idx += 256) {
        int j = idx >> 6, n = idx & 63;
        BdT[n][j] = (__bf16)((float)Bsh[j * 64 + n] * decs[j]);
    }
    __syncthreads();
    const int fr = lane & 15, fk = (lane >> 4) * 8;
    const int mt  = wave >> 1;
    const int ntb = (wave & 1) * 2;
    f32x4 acc[2] = {};
    const __bf16* xrow = xdtT + bch * 8192;
#pragma unroll
    for (int ks = 0; ks < 8; ++ks) {
        bf16x8 af = *(const bf16x8*)&xrow[(mt * 16 + fr) * 256 + ks * 32 + fk];
#pragma unroll
        for (int nb = 0; nb < 2; ++nb) {
            bf16x8 bfv = *(const bf16x8*)&BdT[(ntb + nb) * 16 + fr][ks * 32 + fk];
            acc[nb] = MFMA16(af, bfv, acc[nb]);
        }
    }
    const int rowb = (lane >> 4) * 4;
#pragma unroll
    for (int nb = 0; nb < 2; ++nb)
#pragma unroll
        for (int q = 0; q < 4; ++q) {
            int p = mt * 16 + rowb + q;
            int n = (ntb + nb) * 16 + fr;
            states[bch * 2048 + p * 64 + n] = acc[nb][q];
        }
}

// ---------------------------------------------------------------------------
// scan: prev[b,c] = prev[b,c-1]*exp(alast[c-1]) + states[c-1]; bf16 out.
// ---------------------------------------------------------------------------
__global__ void scan_kernel(const float* __restrict__ states,
                            const float* __restrict__ acum,
                            __bf16* __restrict__ prevbf)
{
    int t = blockIdx.x * 256 + threadIdx.x;
    int n = t & 63, p = (t >> 6) & 31, h = (t >> 11) & 31, b = t >> 16;
    float s = 0.f;
    for (int c = 0; c < 16; ++c) {
        size_t bch = ((size_t)(b * 16 + c) * 32 + h);
        size_t off = bch * 2048 + (size_t)p * 64 + n;
        prevbf[off] = (__bf16)s;
        float dec = __expf(acum[bch * 256 + 255]);
        s = s * dec + states[off];
    }
}

// ---------------------------------------------------------------------------
// y: block=(b,c,h); 4 waves; wave w owns row-subtiles si in {w,w+4,w+8,w+12}.
//   Stage B[256x64], xdtT[32x256] (XOR chunk-swizzled) async; one barrier.
//   Per (jt,si): S=C@B^T (8 MFMA) -> decay/mask -> wave-private Gw -> Y += xa@G
//   Off-term: scaled C-frags used directly as B-operand vs prev-frags.
// ---------------------------------------------------------------------------
__global__ __launch_bounds__(256, 2) void y_kernel(
    const __bf16* __restrict__ Bbf, const __bf16* __restrict__ Cbf,
    const float* __restrict__ acum, const __bf16* __restrict__ xdtT,
    const __bf16* __restrict__ prevbf, const float* __restrict__ xbcdt,
    const float* __restrict__ Dp, __bf16* __restrict__ ybf)
{
    const int bidx = blockIdx.x;
    const int bc = bidx & 31, h = bidx >> 5;   // same-bc blocks -> same XCD
    const size_t bch = (size_t)bc * 32 + h;
    __shared__ __attribute__((aligned(16))) __bf16 Bsh[256 * 64];   // 32 KB
    __shared__ __attribute__((aligned(16))) __bf16 xsh[32 * 256];   // 16 KB
    __shared__ __attribute__((aligned(16))) __bf16 Gw[4][16 * 72];  //  9 KB
    __shared__ float ash[256];
    const int t = threadIdx.x, w = t >> 6, lane = t & 63;
    const int fr = lane & 15, q = lane >> 4;

    // ---- async staging (chunk-swizzled for conflict-free b128 reads)
    const __bf16* Bsrc = Bbf + (size_t)bc * 16384;
#pragma unroll
    for (int cc = 0; cc < 8; ++cc) {
        int s = w * 8 + cc;
        int row = s * 8 + (lane >> 3);
        int ch = (lane & 7) ^ ((lane >> 3) & 7);
        async_copy16(Bsrc + row * 64 + ch * 8, Bsh + s * 512);
    }
    const __bf16* xsrc = xdtT + bch * 8192;
#pragma unroll
    for (int cc = 0; cc < 4; ++cc) {
        int s = w * 4 + cc;
        int p = s * 2 + (lane >> 5);
        int cl = lane & 31;
        int ch = (cl & 24) | ((cl & 7) ^ (p & 7));
        async_copy16(xsrc + p * 256 + ch * 8, xsh + s * 512);
    }
    ash[t] = acum[bch * 256 + t];
    __syncthreads();   // the ONLY barrier

    // ---- hoisted fragments
    bf16x8 cf[4][2], pf[2][2];
    float ei4[4];
#pragma unroll
    for (int s4 = 0; s4 < 4; ++s4) {
        int i = (w + 4 * s4) * 16 + fr;
        const __bf16* cp = Cbf + ((size_t)bc * 256 + i) * 64 + q * 8;
        cf[s4][0] = *(const bf16x8*)cp;
        cf[s4][1] = *(const bf16x8*)(cp + 32);
        ei4[s4] = __expf(ash[i]);
    }
#pragma unroll
    for (int mt = 0; mt < 2; ++mt) {
        const __bf16* pp = prevbf + bch * 2048 + (size_t)(mt * 16 + fr) * 64 + q * 8;
        pf[mt][0] = *(const bf16x8*)pp;
        pf[mt][1] = *(const bf16x8*)(pp + 32);
    }
    float ai[4][4];
#pragma unroll
    for (int s4 = 0; s4 < 4; ++s4)
#pragma unroll
        for (int r = 0; r < 4; ++r)
            ai[s4][r] = ash[(w + 4 * s4) * 16 + q * 4 + r];

    f32x4 acc[4][2] = {};

#pragma unroll
    for (int jt = 0; jt < 4; ++jt) {
        bf16x8 bb[4][2], xa[2][2];
#pragma unroll
        for (int nt = 0; nt < 4; ++nt) {
            int j = jt * 64 + nt * 16 + fr;
#pragma unroll
            for (int ks = 0; ks < 2; ++ks) {
                int ch = (q + 4 * ks) ^ (fr & 7);
                bb[nt][ks] = *(const bf16x8*)&Bsh[j * 64 + ch * 8];
            }
        }
#pragma unroll
        for (int mt = 0; mt < 2; ++mt) {
            int p = mt * 16 + fr;
#pragma unroll
            for (int ks = 0; ks < 2; ++ks) {
                int ch = 8 * jt + ((q + 4 * ks) ^ (p & 7));
                xa[mt][ks] = *(const bf16x8*)&xsh[p * 256 + ch * 8];
            }
        }
#pragma unroll
        for (int s4 = 0; s4 < 4; ++s4) {
            int si = w + 4 * s4;
            if (si < 4 * jt) continue;
            // phase 1: S[16x64] = C_si @ B_jt^T
            f32x4 sreg[4];
#pragma unroll
            for (int nt = 0; nt < 4; ++nt) {
                f32x4 z = {};
                z = MFMA16(cf[s4][0], bb[nt][0], z);
                z = MFMA16(cf[s4][1], bb[nt][1], z);
                sreg[nt] = z;
            }
            // decay + mask -> wave-private Gw
#pragma unroll
            for (int nt = 0; nt < 4; ++nt) {
                int j = jt * 64 + nt * 16 + fr;
                float aj = ash[j];
#pragma unroll
                for (int r = 0; r < 4; ++r) {
                    int i = si * 16 + q * 4 + r;
                    float v = (j <= i) ? sreg[nt][r] * __expf(ai[s4][r] - aj) : 0.f;
                    Gw[w][(q * 4 + r) * 72 + nt * 16 + fr] = (__bf16)v;
                }
            }
            // phase 2: Y[p][i] += xdt_jt @ G^T  (same-wave LDS, no barrier)
            bf16x8 g0 = *(const bf16x8*)&Gw[w][fr * 72 + q * 8];
            bf16x8 g1 = *(const bf16x8*)&Gw[w][fr * 72 + 32 + q * 8];
#pragma unroll
            for (int mt = 0; mt < 2; ++mt) {
                acc[s4][mt] = MFMA16(xa[mt][0], g0, acc[s4][mt]);
                acc[s4][mt] = MFMA16(xa[mt][1], g1, acc[s4][mt]);
            }
        }
    }

    // ---- off-term: scaled C-frags directly as B-operand (A/B layouts match)
#pragma unroll
    for (int s4 = 0; s4 < 4; ++s4) {
#pragma unroll
        for (int ks = 0; ks < 2; ++ks) {
            bf16x8 ce;
#pragma unroll
            for (int e = 0; e < 8; ++e)
                ce[e] = (__bf16)((float)cf[s4][ks][e] * ei4[s4]);
#pragma unroll
            for (int mt = 0; mt < 2; ++mt)
                acc[s4][mt] = MFMA16(pf[mt][ks], ce, acc[s4][mt]);
        }
    }

    // ---- epilogue: + x*D, bf16x4 stores
    const float Dv = Dp[h];
#pragma unroll
    for (int s4 = 0; s4 < 4; ++s4) {
        int i = (w + 4 * s4) * 16 + fr;
        size_t row = (size_t)bc * 256 + i;
#pragma unroll
        for (int mt = 0; mt < 2; ++mt) {
            int p0 = mt * 16 + q * 4;
            float4 xv = *(const float4*)&xbcdt[row * 1184 + h * 32 + p0];
            bf16x4 o;
            o[0] = (__bf16)(acc[s4][mt][0] + xv.x * Dv);
            o[1] = (__bf16)(acc[s4][mt][1] + xv.y * Dv);
            o[2] = (__bf16)(acc[s4][mt][2] + xv.z * Dv);
            o[3] = (__bf16)(acc[s4][mt][3] + xv.w * Dv);
            *(bf16x4*)&ybf[row * 1024 + h * 32 + p0] = o;
        }
    }
}

// ---------------------------------------------------------------------------
extern "C" void kernel_launch(void* const* d_in, const int* in_sizes, int n_in,
                              void* d_out, int out_size, void* d_ws, size_t ws_size,
                              hipStream_t stream)
{
    (void)in_sizes; (void)n_in; (void)out_size;
    const float* u       = (const float*)d_in[0];
    const float* W_in    = (const float*)d_in[1];
    const float* dt_bias = (const float*)d_in[2];
    const float* A_log   = (const float*)d_in[3];
    const float* Dp      = (const float*)d_in[4];
    const float* W_out   = (const float*)d_in[5];
    float* out = (float*)d_out;

    if (ws_size < 93650944) return;

    char* ws = (char*)d_ws;
    __bf16* u_bf    = (__bf16*)(ws);                  // 16,777,216 (reused as ybf)
    __bf16* win_bf  = (__bf16*)(ws + 16777216);       //  2,424,832
    __bf16* wout_bf = (__bf16*)(ws + 19202048);       //  2,097,152
    float*  xbcdt   = (float*) (ws + 21299200);       // 38,797,312
    float*  dtb     = (float*) (ws + 60096512);       //  1,048,576
    float*  acum    = (float*) (ws + 61145088);       //  1,048,576
    __bf16* xdtT    = (__bf16*)(ws + 62193664);       // 16,777,216
    float*  states  = (float*) (ws + 78970880);       //  8,388,608
    __bf16* prevbf  = (__bf16*)(ws + 87359488);       //  4,194,304
    __bf16* Bbf     = (__bf16*)(ws + 91553792);       //  1,048,576
    __bf16* Cbf     = (__bf16*)(ws + 92602368);       //  1,048,576

    cvt_f32_bf16<<<8192, 256, 0, stream>>>(u, u_bf, 8388608);
    cvt_f32_bf16<<<1184, 256, 0, stream>>>(W_in, win_bf, 1212416);
    cvt_f32_bf16<<<1024, 256, 0, stream>>>(W_out, wout_bf, 1048576);

    gemm_bt<<<dim3(10, 64), 256, 0, stream>>>(u_bf, win_bf, xbcdt, 1024, 1184, 1184);

    prep_kernel<<<dim3(32, 16, 2), 256, 0, stream>>>(xbcdt, dt_bias, A_log, dtb, acum);
    bc_cvt<<<4096, 256, 0, stream>>>(xbcdt, Bbf, Cbf);
    xdtt_kernel<<<dim3(32, 16, 2), 256, 0, stream>>>(xbcdt, dtb, xdtT);
    states_kernel<<<dim3(32, 16, 2), 256, 0, stream>>>(Bbf, acum, xdtT, states);
    scan_kernel<<<512, 256, 0, stream>>>(states, acum, prevbf);

    __bf16* ybf = u_bf;  // u_bf dead after gemm1
    y_kernel<<<1024, 256, 0, stream>>>(Bbf, Cbf, acum, xdtT, prevbf,
                                       xbcdt, Dp, ybf);

    gemm_bt<<<dim3(8, 64), 256, 0, stream>>>(ybf, wout_bf, out, 1024, 1024, 1024);
}